// Round 2
// baseline (362.369 us; speedup 1.0000x reference)
//
#include <hip/hip_runtime.h>
#include <math.h>

#define NROWS 32768
#define NE    1024
#define CDIM  256
#define ZB_STRIDE 262144

#define ZQ_OFF   0
#define LOSS_OFF 8388608
#define PERP_OFF 8388609
#define ENC_OFF  8388610
#define IDX_OFF  41943042

#define THETA 2.5e-4f

typedef __attribute__((ext_vector_type(8))) short bf16x8;
typedef __attribute__((ext_vector_type(4))) float f32x4;
typedef __attribute__((ext_vector_type(8))) unsigned short ushort8;

// RNE float -> bf16 bits
__device__ __forceinline__ unsigned short f2bf(float f) {
  union { float f; unsigned u; } v; v.f = f;
  unsigned r = v.u + 0x7FFFu + ((v.u >> 16) & 1u);
  return (unsigned short)(r >> 16);
}

// async global->LDS, 16B per lane; lds dest is wave-uniform-base + lane*16
__device__ __forceinline__ void gl_lds16(const unsigned short* g, char* l) {
  __builtin_amdgcn_global_load_lds(
      (const __attribute__((address_space(1))) unsigned short*)g,
      (__attribute__((address_space(3))) char*)l, 16, 0, 0);
}

// ---------------------------------------------------------------------------
// numpy-pairwise-exact sum of squares (stride 1) for embeddings
__device__ __forceinline__ float np_sumsq_256_s1(const float* __restrict__ base) {
  float tot[2];
#pragma unroll
  for (int hh = 0; hh < 2; ++hh) {
    float r[8];
#pragma unroll
    for (int j = 0; j < 8; ++j) {
      float x = base[hh * 128 + j];
      r[j] = __fmul_rn(x, x);
    }
    for (int i = 8; i < 128; i += 8) {
#pragma unroll
      for (int j = 0; j < 8; ++j) {
        float x = base[hh * 128 + i + j];
        r[j] = __fadd_rn(r[j], __fmul_rn(x, x));
      }
    }
    tot[hh] = __fadd_rn(__fadd_rn(__fadd_rn(r[0], r[1]), __fadd_rn(r[2], r[3])),
                        __fadd_rn(__fadd_rn(r[4], r[5]), __fadd_rn(r[6], r[7])));
  }
  return __fadd_rn(tot[0], tot[1]);
}

__global__ __launch_bounds__(256) void enorm_kernel(const float* __restrict__ emb,
                                                    float* __restrict__ enorm) {
  int n = blockIdx.x * 256 + threadIdx.x;
  enorm[n] = np_sumsq_256_s1(emb + (size_t)n * CDIM);
}

// emb fp32 -> bf16 (row-major unchanged)
__global__ __launch_bounds__(256) void convert_e_kernel(const float* __restrict__ emb,
                                                        unsigned short* __restrict__ ehi) {
  int i = (blockIdx.x * 256 + threadIdx.x) * 8;
  ushort8 o;
#pragma unroll
  for (int j = 0; j < 8; ++j) o[j] = f2bf(emb[i + j]);
  *reinterpret_cast<ushort8*>(ehi + i) = o;
}

// ---------------------------------------------------------------------------
// z (b,c,h,w) fp32 -> zhi (n,c) bf16 transpose + numpy-exact znorm.
// Block: one b, one 64-wide hw tile. Threads: hw = t&63 (coalesced), r = t>>6
// owns c = r + 4u. np pairwise 8-acc structure: acc_j (j = c mod 8 per half)
// distributed as: thread r holds j=r (u even) and j=r+4 (u odd) per half.
__global__ __launch_bounds__(256) void convert_z_kernel(const float* __restrict__ z,
                                                        unsigned short* __restrict__ zhi,
                                                        float* __restrict__ znorm) {
  __shared__ unsigned short T16[64][266];
  __shared__ float accs[64][17];
  const int t = threadIdx.x;
  const int b = blockIdx.x >> 4, hwt = blockIdx.x & 15;
  const int hw0 = hwt * 64;
  const int hw = t & 63, r = t >> 6;
  const float* zb = z + (size_t)b * ZB_STRIDE + hw0 + hw;

  float a00 = 0.f, a01 = 0.f, a10 = 0.f, a11 = 0.f;
#pragma unroll
  for (int u = 0; u < 64; ++u) {
    int c = r + 4 * u;
    float x = zb[(size_t)c * 1024];
    float p = __fmul_rn(x, x);
    if (u < 32) { if ((u & 1) == 0) a00 = __fadd_rn(a00, p); else a01 = __fadd_rn(a01, p); }
    else        { if ((u & 1) == 0) a10 = __fadd_rn(a10, p); else a11 = __fadd_rn(a11, p); }
    T16[hw][c] = f2bf(x);
  }
  accs[hw][r]     = a00; accs[hw][r + 4]  = a01;
  accs[hw][8 + r] = a10; accs[hw][12 + r] = a11;
  __syncthreads();

  if (t < 64) {
    const float* A = accs[t];
    float t0 = __fadd_rn(__fadd_rn(__fadd_rn(A[0], A[1]), __fadd_rn(A[2], A[3])),
                         __fadd_rn(__fadd_rn(A[4], A[5]), __fadd_rn(A[6], A[7])));
    float t1 = __fadd_rn(__fadd_rn(__fadd_rn(A[8], A[9]), __fadd_rn(A[10], A[11])),
                         __fadd_rn(__fadd_rn(A[12], A[13]), __fadd_rn(A[14], A[15])));
    znorm[b * 1024 + hw0 + t] = __fadd_rn(t0, t1);
  }

  // write phase: thread -> row hww, 64 c's
  const int hww = t >> 2, cqq = (t & 3) * 64;
  unsigned short* orow = zhi + ((size_t)(b * 1024 + hw0 + hww)) * 256 + cqq;
#pragma unroll
  for (int v = 0; v < 8; ++v) {
    ushort8 o;
#pragma unroll
    for (int j = 0; j < 8; ++j) o[j] = T16[hww][cqq + v * 8 + j];
    *reinterpret_cast<ushort8*>(orow + v * 8) = o;
  }
}

// ---------------------------------------------------------------------------
// MFMA argmin: block = 128 rows x (8 e-tiles of 128), K=256 bf16, BK=64.
// 4 waves in 2x2; wave tile 64x64 = 4x4 frags of 16x16x32.
// LDS 64KB exactly: A,B double-buffered [2][128 rows][128 B], XOR-swizzled.
__global__ __launch_bounds__(256) void argmin_mfma(
    const unsigned short* __restrict__ zhi, const unsigned short* __restrict__ ehi,
    const float* __restrict__ znorm, const float* __restrict__ enorm,
    int* __restrict__ idx_out, float* __restrict__ loss_part,
    int* __restrict__ flag_cnt, int* __restrict__ flag_list) {
  __shared__ __align__(16) char As[2][16384];
  __shared__ __align__(16) char Bs[2][16384];

  const int tid = threadIdx.x;
  const int lane = tid & 63, w = tid >> 6;
  const int wr = w >> 1, wc = w & 1;
  const int l15 = lane & 15, g = lane >> 4;
  const int n0 = blockIdx.x * 128;

  // per-lane row norms: row = n0 + wr*64 + mi*16 + g*4 + rg
  float znr[4][4];
#pragma unroll
  for (int mi = 0; mi < 4; ++mi)
#pragma unroll
    for (int rg = 0; rg < 4; ++rg)
      znr[mi][rg] = znorm[n0 + wr * 64 + mi * 16 + g * 4 + rg];

  float bestd[4][4], b2d[4][4]; int besti[4][4];
#pragma unroll
  for (int mi = 0; mi < 4; ++mi)
#pragma unroll
    for (int rg = 0; rg < 4; ++rg) { bestd[mi][rg] = 3.4e38f; b2d[mi][rg] = 3.4e38f; besti[mi][rg] = 0; }

  // staging helpers: tile row stride 128 B; source pre-swizzled (rule 21)
#define STAGE_A(kt, buf)                                                        \
  {                                                                             \
    _Pragma("unroll")                                                           \
    for (int i = 0; i < 4; ++i) {                                               \
      int off = w * 4096 + i * 1024 + lane * 16;                                \
      int row = off >> 7, c = off & 127;                                        \
      int csrc = ((kt) << 7) + (c ^ ((row & 7) << 4));                          \
      gl_lds16(zhi + (((size_t)(n0 + row)) << 8) + (csrc >> 1), As[buf] + off); \
    }                                                                           \
  }
#define STAGE_B(et, kt, buf)                                                    \
  {                                                                             \
    int e0s = (et) * 128;                                                       \
    _Pragma("unroll")                                                           \
    for (int i = 0; i < 4; ++i) {                                               \
      int off = w * 4096 + i * 1024 + lane * 16;                                \
      int row = off >> 7, c = off & 127;                                        \
      int csrc = ((kt) << 7) + (c ^ ((row & 7) << 4));                          \
      gl_lds16(ehi + (((size_t)(e0s + row)) << 8) + (csrc >> 1), Bs[buf] + off);\
    }                                                                           \
  }

  STAGE_A(0, 0);
  STAGE_B(0, 0, 0);
  __syncthreads();

  f32x4 acc[4][4];
  int s = 0;
  for (int et = 0; et < 8; ++et) {
    const f32x4 z4 = {0.f, 0.f, 0.f, 0.f};
#pragma unroll
    for (int mi = 0; mi < 4; ++mi)
#pragma unroll
      for (int nj = 0; nj < 4; ++nj) acc[mi][nj] = z4;

    for (int kt = 0; kt < 4; ++kt, ++s) {
      const int buf = s & 1;
      if (s + 1 < 32) {
        const int ns = s + 1, nkt = ns & 3, net = ns >> 2;
        STAGE_A(nkt, buf ^ 1);
        STAGE_B(net, nkt, buf ^ 1);
      }
      // compute on current buffers
#pragma unroll
      for (int ks = 0; ks < 2; ++ks) {
        bf16x8 af[4], bv[4];
#pragma unroll
        for (int mi = 0; mi < 4; ++mi) {
          int rr = wr * 64 + mi * 16 + l15;
          int cc = (ks * 64 + g * 16) ^ ((rr & 7) << 4);
          af[mi] = *reinterpret_cast<const bf16x8*>(&As[buf][rr * 128 + cc]);
        }
#pragma unroll
        for (int nj = 0; nj < 4; ++nj) {
          int er = wc * 64 + nj * 16 + l15;
          int cc = (ks * 64 + g * 16) ^ ((er & 7) << 4);
          bv[nj] = *reinterpret_cast<const bf16x8*>(&Bs[buf][er * 128 + cc]);
        }
#pragma unroll
        for (int mi = 0; mi < 4; ++mi)
#pragma unroll
          for (int nj = 0; nj < 4; ++nj)
            acc[mi][nj] = __builtin_amdgcn_mfma_f32_16x16x32_bf16(af[mi], bv[nj], acc[mi][nj], 0, 0, 0);
      }
      __syncthreads();
    }

    // epilogue: d = (zn + en) - 2*dot, top-2 running min (e ascending)
#pragma unroll
    for (int nj = 0; nj < 4; ++nj) {
      int e = et * 128 + wc * 64 + nj * 16 + l15;
      float en = enorm[e];
#pragma unroll
      for (int mi = 0; mi < 4; ++mi)
#pragma unroll
        for (int rg = 0; rg < 4; ++rg) {
          float d = fmaf(-2.0f, acc[mi][nj][rg], znr[mi][rg] + en);
          if (d < bestd[mi][rg]) {
            b2d[mi][rg] = bestd[mi][rg]; bestd[mi][rg] = d; besti[mi][rg] = e;
          } else if (d < b2d[mi][rg]) {
            b2d[mi][rg] = d;
          }
        }
    }
  }

  // cross-lane merge (16 lanes share rows), then cross-wave merge via LDS
  float* redd = reinterpret_cast<float*>(&As[0][0]);        // 256 floats
  int*   redi = reinterpret_cast<int*>(&As[0][0] + 1024);   // 256 ints
  float* red2 = reinterpret_cast<float*>(&As[0][0] + 2048); // 256 floats

#pragma unroll
  for (int mi = 0; mi < 4; ++mi)
#pragma unroll
    for (int rg = 0; rg < 4; ++rg) {
      float bd = bestd[mi][rg]; int bi = besti[mi][rg]; float b2 = b2d[mi][rg];
#pragma unroll
      for (int m = 1; m < 16; m <<= 1) {
        float od = __shfl_xor(bd, m, 64);
        int   oi = __shfl_xor(bi, m, 64);
        float o2 = __shfl_xor(b2, m, 64);
        float hi = fmaxf(bd, od);
        b2 = fminf(fminf(b2, o2), hi);
        if (od < bd || (od == bd && oi < bi)) { bd = od; bi = oi; }
      }
      if (l15 == 0) {
        int lr = wr * 64 + mi * 16 + g * 4 + rg;
        redd[lr * 2 + wc] = bd; redi[lr * 2 + wc] = bi; red2[lr * 2 + wc] = b2;
      }
    }
  __syncthreads();

  if (tid < 128) {
    float d0 = redd[tid * 2], d1 = redd[tid * 2 + 1];
    int   i0 = redi[tid * 2], i1 = redi[tid * 2 + 1];
    float s0 = red2[tid * 2], s1 = red2[tid * 2 + 1];
    float bd; int bi;
    if (d1 < d0 || (d1 == d0 && i1 < i0)) { bd = d1; bi = i1; } else { bd = d0; bi = i0; }
    float b2 = fminf(fminf(s0, s1), fmaxf(d0, d1));
    int rrow = n0 + tid;
    idx_out[rrow] = bi;
    loss_part[rrow] = bd;
    if (b2 - bd < THETA) {
      int p = atomicAdd(flag_cnt, 1);
      flag_list[p] = rrow;
    }
  }
#undef STAGE_A
#undef STAGE_B
}

// ---------------------------------------------------------------------------
// exact-fp32 repair for flagged rows: replicates round-1-validated arithmetic
__global__ __launch_bounds__(256) void repair_kernel(
    const float* __restrict__ z, const float* __restrict__ emb,
    const float* __restrict__ znorm, const float* __restrict__ enorm,
    const int* __restrict__ flag_cnt, const int* __restrict__ flag_list,
    int* __restrict__ idx_out) {
  __shared__ float zrow[256];
  __shared__ float rd[256];
  __shared__ int   ri[256];
  const int t = threadIdx.x;
  const int cnt = flag_cnt[0] < NROWS ? flag_cnt[0] : NROWS;
  for (int j = blockIdx.x; j < cnt; j += gridDim.x) {
    const int n = flag_list[j];
    __syncthreads();
    zrow[t] = z[(size_t)(n >> 10) * ZB_STRIDE + (size_t)t * 1024 + (n & 1023)];
    __syncthreads();
    const float zn = znorm[n];
    float bd = 3.4e38f; int bi = 0;
#pragma unroll
    for (int u = 0; u < 4; ++u) {
      const int e = u * 256 + t;
      const float* er = emb + (size_t)e * 256;
      float dot = 0.f;
      for (int k = 0; k < 256; ++k) dot = fmaf(zrow[k], er[k], dot);
      float d = __fsub_rn(__fadd_rn(zn, enorm[e]), __fmul_rn(2.0f, dot));
      if (d < bd) { bd = d; bi = e; }
    }
    rd[t] = bd; ri[t] = bi;
    __syncthreads();
    for (int s2 = 128; s2 > 0; s2 >>= 1) {
      if (t < s2) {
        float od = rd[t + s2]; int oi = ri[t + s2];
        if (od < rd[t] || (od == rd[t] && oi < ri[t])) { rd[t] = od; ri[t] = oi; }
      }
      __syncthreads();
    }
    if (t == 0) idx_out[n] = ri[0];
  }
}

// ---------------------------------------------------------------------------
// one-hot: streaming write of the whole 134MB region (replaces memset+scatter)
__global__ __launch_bounds__(256) void onehot_kernel(const int* __restrict__ idx,
                                                     float* __restrict__ out_enc) {
  for (int i = blockIdx.x * 256 + threadIdx.x; i < NROWS * 256; i += 2048 * 256) {
    int n = i >> 8, j4 = i & 255;
    int e = idx[n];
    float4 v = {0.f, 0.f, 0.f, 0.f};
    if ((e >> 2) == j4) ((float*)&v)[e & 3] = 1.0f;
    reinterpret_cast<float4*>(out_enc)[i] = v;
  }
}

__global__ __launch_bounds__(256) void idxf_hist_kernel(const int* __restrict__ idx,
                                                        float* __restrict__ out_idxf,
                                                        int* __restrict__ hist) {
  int n = blockIdx.x * 256 + threadIdx.x;
  int e = idx[n];
  out_idxf[n] = (float)e;
  atomicAdd(&hist[e], 1);
}

// gather z_q into (b,c,h,w)
__global__ __launch_bounds__(256) void gather_kernel(const float* __restrict__ emb,
                                                     const int* __restrict__ idx,
                                                     float* __restrict__ zq_out) {
  int bh = blockIdx.x;
  int b = bh >> 5, h = bh & 31;
  int t = threadIdx.x;
  int ww = t & 31;
  int gg = t >> 5;
  int n = b * 1024 + h * 32 + ww;
  int e = idx[n];
  const float* eb = emb + (size_t)e * CDIM;
  float* ob = zq_out + (size_t)b * ZB_STRIDE + h * 32 + ww;
#pragma unroll
  for (int u = 0; u < 32; ++u) {
    int c = gg * 32 + u;
    ob[(size_t)c * 1024] = eb[c];
  }
}

__global__ __launch_bounds__(256) void finalize_kernel(const float* __restrict__ loss_part,
                                                       const int* __restrict__ hist,
                                                       float* __restrict__ out_loss,
                                                       float* __restrict__ out_perp) {
  __shared__ float red[256];
  int t = threadIdx.x;
  float sum = 0.f;
  for (int i = t; i < NROWS; i += 256) sum += loss_part[i];
  red[t] = sum;
  __syncthreads();
  for (int s2 = 128; s2 > 0; s2 >>= 1) {
    if (t < s2) red[t] += red[t + s2];
    __syncthreads();
  }
  if (t == 0) out_loss[0] = 1.25f * (red[0] / 8388608.0f);
  __syncthreads();
  float hs = 0.f;
  for (int i = t; i < 1024; i += 256) {
    float em = (float)hist[i] / 32768.0f;
    hs += em * logf(em + 1e-10f);
  }
  red[t] = hs;
  __syncthreads();
  for (int s2 = 128; s2 > 0; s2 >>= 1) {
    if (t < s2) red[t] += red[t + s2];
    __syncthreads();
  }
  if (t == 0) out_perp[0] = expf(-red[0]);
}

// ---------------------------------------------------------------------------
extern "C" void kernel_launch(void* const* d_in, const int* in_sizes, int n_in,
                              void* d_out, int out_size, void* d_ws, size_t ws_size,
                              hipStream_t stream) {
  const float* z   = (const float*)d_in[0];
  const float* emb = (const float*)d_in[1];
  float* out = (float*)d_out;

  float* out_zq   = out + ZQ_OFF;
  float* out_loss = out + LOSS_OFF;
  float* out_perp = out + PERP_OFF;
  float* out_enc  = out + ENC_OFF;
  float* out_idxf = out + IDX_OFF;

  // workspace (small)
  int*   idx       = (int*)d_ws;                   // 32768
  int*   hist      = idx + NROWS;                  // 1024
  int*   flag_cnt  = hist + NE;                    // 4 (1 used)
  int*   flag_list = flag_cnt + 4;                 // 32768
  float* loss_part = (float*)(flag_list + NROWS);  // 32768
  float* znorm     = loss_part + NROWS;            // 32768
  float* enorm     = znorm + NROWS;                // 1024

  // bf16 operands carved from the one-hot output region (overwritten later);
  // +2 floats to make the base 16B-aligned
  unsigned short* zhi = (unsigned short*)(out_enc + 2);   // 8.4M u16
  unsigned short* ehi = zhi + (size_t)NROWS * CDIM;       // 0.26M u16

  hipMemsetAsync(hist, 0, NE * sizeof(int), stream);
  hipMemsetAsync(flag_cnt, 0, sizeof(int), stream);

  convert_z_kernel<<<512, 256, 0, stream>>>(z, zhi, znorm);
  convert_e_kernel<<<128, 256, 0, stream>>>(emb, ehi);
  enorm_kernel<<<NE / 256, 256, 0, stream>>>(emb, enorm);
  argmin_mfma<<<NROWS / 128, 256, 0, stream>>>(zhi, ehi, znorm, enorm,
                                               idx, loss_part, flag_cnt, flag_list);
  repair_kernel<<<512, 256, 0, stream>>>(z, emb, znorm, enorm, flag_cnt, flag_list, idx);
  onehot_kernel<<<2048, 256, 0, stream>>>(idx, out_enc);
  idxf_hist_kernel<<<NROWS / 256, 256, 0, stream>>>(idx, out_idxf, hist);
  gather_kernel<<<1024, 256, 0, stream>>>(emb, idx, out_zq);
  finalize_kernel<<<1, 256, 0, stream>>>(loss_part, hist, out_loss, out_perp);
}

// Round 3
// 309.126 us; speedup vs baseline: 1.1722x; 1.1722x over previous
//
#include <hip/hip_runtime.h>
#include <math.h>

#define NROWS 32768
#define NE    1024
#define CDIM  256
#define ZB_STRIDE 262144

#define ZQ_OFF   0
#define LOSS_OFF 8388608
#define PERP_OFF 8388609
#define ENC_OFF  8388610
#define IDX_OFF  41943042

#define THETA 1.0e-4f

typedef __attribute__((ext_vector_type(8))) short bf16x8;
typedef __attribute__((ext_vector_type(4))) float f32x4;
typedef __attribute__((ext_vector_type(8))) unsigned short ushort8;

// RNE float -> bf16 bits
__device__ __forceinline__ unsigned short f2bf(float f) {
  union { float f; unsigned u; } v; v.f = f;
  unsigned r = v.u + 0x7FFFu + ((v.u >> 16) & 1u);
  return (unsigned short)(r >> 16);
}
__device__ __forceinline__ float bf2f(unsigned short b) {
  union { float f; unsigned u; } v; v.u = ((unsigned)b) << 16;
  return v.f;
}

// async global->LDS, 16B per lane
__device__ __forceinline__ void gl_lds16(const unsigned short* g, char* l) {
  __builtin_amdgcn_global_load_lds(
      (const __attribute__((address_space(1))) unsigned short*)g,
      (__attribute__((address_space(3))) char*)l, 16, 0, 0);
}

// ---------------------------------------------------------------------------
// numpy-pairwise-exact sum of squares (stride 1)
__device__ __forceinline__ float np_sumsq_256_s1(const float* __restrict__ base) {
  float tot[2];
#pragma unroll
  for (int hh = 0; hh < 2; ++hh) {
    float r[8];
#pragma unroll
    for (int j = 0; j < 8; ++j) {
      float x = base[hh * 128 + j];
      r[j] = __fmul_rn(x, x);
    }
    for (int i = 8; i < 128; i += 8) {
#pragma unroll
      for (int j = 0; j < 8; ++j) {
        float x = base[hh * 128 + i + j];
        r[j] = __fadd_rn(r[j], __fmul_rn(x, x));
      }
    }
    tot[hh] = __fadd_rn(__fadd_rn(__fadd_rn(r[0], r[1]), __fadd_rn(r[2], r[3])),
                        __fadd_rn(__fadd_rn(r[4], r[5]), __fadd_rn(r[6], r[7])));
  }
  return __fadd_rn(tot[0], tot[1]);
}

__global__ __launch_bounds__(256) void enorm_kernel(const float* __restrict__ emb,
                                                    float* __restrict__ enorm) {
  int n = blockIdx.x * 256 + threadIdx.x;
  enorm[n] = np_sumsq_256_s1(emb + (size_t)n * CDIM);
}

// emb fp32 -> bf16 hi + lo (row-major unchanged)
__global__ __launch_bounds__(256) void convert_e_kernel(const float* __restrict__ emb,
                                                        unsigned short* __restrict__ ehi,
                                                        unsigned short* __restrict__ elo) {
  int i = (blockIdx.x * 256 + threadIdx.x) * 8;
  ushort8 oh, ol;
#pragma unroll
  for (int j = 0; j < 8; ++j) {
    float x = emb[i + j];
    unsigned short h = f2bf(x);
    oh[j] = h;
    ol[j] = f2bf(__fsub_rn(x, bf2f(h)));
  }
  *reinterpret_cast<ushort8*>(ehi + i) = oh;
  *reinterpret_cast<ushort8*>(elo + i) = ol;
}

// emb[e][c] -> embT[c][e] fp32 (for coalesced repair)
__global__ __launch_bounds__(256) void transpose_e_kernel(const float* __restrict__ emb,
                                                          float* __restrict__ embT) {
  __shared__ float tile[32][33];
  int be = blockIdx.x & 31, bc = blockIdx.x >> 5;
  int tx = threadIdx.x & 31, ty = threadIdx.x >> 5;
#pragma unroll
  for (int i = 0; i < 4; ++i)
    tile[ty + 8 * i][tx] = emb[(size_t)(be * 32 + ty + 8 * i) * 256 + bc * 32 + tx];
  __syncthreads();
#pragma unroll
  for (int i = 0; i < 4; ++i)
    embT[(size_t)(bc * 32 + ty + 8 * i) * 1024 + be * 32 + tx] = tile[tx][ty + 8 * i];
}

// ---------------------------------------------------------------------------
// z (b,c,h,w) fp32 -> zhi,zlo (n,c) bf16 transpose + numpy-exact znorm.
__global__ __launch_bounds__(256) void convert_z_kernel(const float* __restrict__ z,
                                                        unsigned short* __restrict__ zhi,
                                                        unsigned short* __restrict__ zlo,
                                                        float* __restrict__ znorm) {
  __shared__ unsigned short T16[64][266];
  __shared__ unsigned short Tlo[64][266];
  __shared__ float accs[64][17];
  const int t = threadIdx.x;
  const int b = blockIdx.x >> 4, hwt = blockIdx.x & 15;
  const int hw0 = hwt * 64;
  const int hw = t & 63, r = t >> 6;
  const float* zb = z + (size_t)b * ZB_STRIDE + hw0 + hw;

  float a00 = 0.f, a01 = 0.f, a10 = 0.f, a11 = 0.f;
#pragma unroll
  for (int u = 0; u < 64; ++u) {
    int c = r + 4 * u;
    float x = zb[(size_t)c * 1024];
    float p = __fmul_rn(x, x);
    if (u < 32) { if ((u & 1) == 0) a00 = __fadd_rn(a00, p); else a01 = __fadd_rn(a01, p); }
    else        { if ((u & 1) == 0) a10 = __fadd_rn(a10, p); else a11 = __fadd_rn(a11, p); }
    unsigned short h = f2bf(x);
    T16[hw][c] = h;
    Tlo[hw][c] = f2bf(__fsub_rn(x, bf2f(h)));
  }
  accs[hw][r]     = a00; accs[hw][r + 4]  = a01;
  accs[hw][8 + r] = a10; accs[hw][12 + r] = a11;
  __syncthreads();

  if (t < 64) {
    const float* A = accs[t];
    float t0 = __fadd_rn(__fadd_rn(__fadd_rn(A[0], A[1]), __fadd_rn(A[2], A[3])),
                         __fadd_rn(__fadd_rn(A[4], A[5]), __fadd_rn(A[6], A[7])));
    float t1 = __fadd_rn(__fadd_rn(__fadd_rn(A[8], A[9]), __fadd_rn(A[10], A[11])),
                         __fadd_rn(__fadd_rn(A[12], A[13]), __fadd_rn(A[14], A[15])));
    znorm[b * 1024 + hw0 + t] = __fadd_rn(t0, t1);
  }

  const int hww = t >> 2, cqq = (t & 3) * 64;
  size_t obase = ((size_t)(b * 1024 + hw0 + hww)) * 256 + cqq;
#pragma unroll
  for (int v = 0; v < 8; ++v) {
    ushort8 oh, ol;
#pragma unroll
    for (int j = 0; j < 8; ++j) {
      oh[j] = T16[hww][cqq + v * 8 + j];
      ol[j] = Tlo[hww][cqq + v * 8 + j];
    }
    *reinterpret_cast<ushort8*>(zhi + obase + v * 8) = oh;
    *reinterpret_cast<ushort8*>(zlo + obase + v * 8) = ol;
  }
}

// ---------------------------------------------------------------------------
// Fused 3-product split-bf16 MFMA argmin.
// Block: 128 rows x all 1024 e (8 et tiles of 128). BK=32, double-buffered.
// 4 waves 2x2; wave tile 64x64 = 4x4 frags of 16x16x32.
// dot = zhi.ehi + zhi.elo + zlo.ehi  (error ~3e-7 << np ulp(256)=3e-5)
__global__ __launch_bounds__(256, 2) void argmin_mfma3(
    const unsigned short* __restrict__ zhi, const unsigned short* __restrict__ zlo,
    const unsigned short* __restrict__ ehi, const unsigned short* __restrict__ elo,
    const float* __restrict__ znorm, const float* __restrict__ enorm,
    int* __restrict__ idx_out, float* __restrict__ loss_part,
    int* __restrict__ flag_cnt, int* __restrict__ flag_list) {
  __shared__ __align__(16) char Ah[2][8192];
  __shared__ __align__(16) char Al[2][8192];
  __shared__ __align__(16) char Bh[2][8192];
  __shared__ __align__(16) char Bl[2][8192];

  const int tid = threadIdx.x;
  const int lane = tid & 63, w = tid >> 6;
  const int wr = w >> 1, wc = w & 1;
  const int l15 = lane & 15, g = lane >> 4;
  const int n0 = blockIdx.x * 128;

  float znr[4][4];
#pragma unroll
  for (int mi = 0; mi < 4; ++mi)
#pragma unroll
    for (int rg = 0; rg < 4; ++rg)
      znr[mi][rg] = znorm[n0 + wr * 64 + mi * 16 + g * 4 + rg];

  float bestd[4][4], b2d[4][4]; int besti[4][4];
#pragma unroll
  for (int mi = 0; mi < 4; ++mi)
#pragma unroll
    for (int rg = 0; rg < 4; ++rg) { bestd[mi][rg] = 3.4e38f; b2d[mi][rg] = 3.4e38f; besti[mi][rg] = 0; }

  // stage one 128x32 bf16 tile (8KB): 2 x 16B per thread; 64B rows,
  // swizzle byte ^= ((row>>1)&3)<<4; source pre-swizzled (rule 21)
#define STAGE4(SRC, DST, ROWBASE, KT)                                          \
  {                                                                            \
    _Pragma("unroll")                                                          \
    for (int i = 0; i < 2; ++i) {                                              \
      int off = i * 4096 + tid * 16;                                           \
      int row = off >> 6, cb = off & 63;                                       \
      int csrc = (KT) * 32 + ((cb ^ (((row >> 1) & 3) << 4)) >> 1);            \
      gl_lds16(SRC + (size_t)((ROWBASE) + row) * 256 + csrc, DST + off);       \
    }                                                                          \
  }

  STAGE4(zhi, Ah[0], n0, 0);
  STAGE4(zlo, Al[0], n0, 0);
  STAGE4(ehi, Bh[0], 0, 0);
  STAGE4(elo, Bl[0], 0, 0);
  __syncthreads();

  f32x4 acc[4][4];
  for (int et = 0; et < 8; ++et) {
    const f32x4 z4 = {0.f, 0.f, 0.f, 0.f};
#pragma unroll
    for (int mi = 0; mi < 4; ++mi)
#pragma unroll
      for (int nj = 0; nj < 4; ++nj) acc[mi][nj] = z4;

    for (int kt = 0; kt < 8; ++kt) {
      const int s = et * 8 + kt;
      const int buf = s & 1;
      if (s + 1 < 64) {
        const int ns = s + 1, nkt = ns & 7, net = ns >> 3;
        STAGE4(zhi, Ah[buf ^ 1], n0, nkt);
        STAGE4(zlo, Al[buf ^ 1], n0, nkt);
        STAGE4(ehi, Bh[buf ^ 1], net * 128, nkt);
        STAGE4(elo, Bl[buf ^ 1], net * 128, nkt);
      }
      bf16x8 afh[4], afl[4], bvh[4], bvl[4];
#pragma unroll
      for (int mi = 0; mi < 4; ++mi) {
        int rr = wr * 64 + mi * 16 + l15;
        int cc = (g * 16) ^ (((rr >> 1) & 3) << 4);
        afh[mi] = *reinterpret_cast<const bf16x8*>(&Ah[buf][rr * 64 + cc]);
        afl[mi] = *reinterpret_cast<const bf16x8*>(&Al[buf][rr * 64 + cc]);
      }
#pragma unroll
      for (int nj = 0; nj < 4; ++nj) {
        int er = wc * 64 + nj * 16 + l15;
        int cc = (g * 16) ^ (((er >> 1) & 3) << 4);
        bvh[nj] = *reinterpret_cast<const bf16x8*>(&Bh[buf][er * 64 + cc]);
        bvl[nj] = *reinterpret_cast<const bf16x8*>(&Bl[buf][er * 64 + cc]);
      }
#pragma unroll
      for (int mi = 0; mi < 4; ++mi)
#pragma unroll
        for (int nj = 0; nj < 4; ++nj) {
          acc[mi][nj] = __builtin_amdgcn_mfma_f32_16x16x32_bf16(afl[mi], bvh[nj], acc[mi][nj], 0, 0, 0);
          acc[mi][nj] = __builtin_amdgcn_mfma_f32_16x16x32_bf16(afh[mi], bvl[nj], acc[mi][nj], 0, 0, 0);
          acc[mi][nj] = __builtin_amdgcn_mfma_f32_16x16x32_bf16(afh[mi], bvh[nj], acc[mi][nj], 0, 0, 0);
        }
      __syncthreads();
    }

    // epilogue: d = fl(fl(zn+en) - 2*dot) (x2 exact), top-2, e ascending
#pragma unroll
    for (int nj = 0; nj < 4; ++nj) {
      int e = et * 128 + wc * 64 + nj * 16 + l15;
      float en = enorm[e];
#pragma unroll
      for (int mi = 0; mi < 4; ++mi)
#pragma unroll
        for (int rg = 0; rg < 4; ++rg) {
          float d = fmaf(-2.0f, acc[mi][nj][rg], __fadd_rn(znr[mi][rg], en));
          if (d < bestd[mi][rg]) {
            b2d[mi][rg] = bestd[mi][rg]; bestd[mi][rg] = d; besti[mi][rg] = e;
          } else if (d < b2d[mi][rg]) {
            b2d[mi][rg] = d;
          }
        }
    }
  }

  float* redd = reinterpret_cast<float*>(&Ah[0][0]);
  int*   redi = reinterpret_cast<int*>(&Ah[0][0] + 1024);
  float* red2 = reinterpret_cast<float*>(&Ah[0][0] + 2048);

#pragma unroll
  for (int mi = 0; mi < 4; ++mi)
#pragma unroll
    for (int rg = 0; rg < 4; ++rg) {
      float bd = bestd[mi][rg]; int bi = besti[mi][rg]; float b2 = b2d[mi][rg];
#pragma unroll
      for (int m = 1; m < 16; m <<= 1) {
        float od = __shfl_xor(bd, m, 64);
        int   oi = __shfl_xor(bi, m, 64);
        float o2 = __shfl_xor(b2, m, 64);
        float hi = fmaxf(bd, od);
        b2 = fminf(fminf(b2, o2), hi);
        if (od < bd || (od == bd && oi < bi)) { bd = od; bi = oi; }
      }
      if (l15 == 0) {
        int lr = wr * 64 + mi * 16 + g * 4 + rg;
        redd[lr * 2 + wc] = bd; redi[lr * 2 + wc] = bi; red2[lr * 2 + wc] = b2;
      }
    }
  __syncthreads();

  if (tid < 128) {
    float d0 = redd[tid * 2], d1 = redd[tid * 2 + 1];
    int   i0 = redi[tid * 2], i1 = redi[tid * 2 + 1];
    float s0 = red2[tid * 2], s1 = red2[tid * 2 + 1];
    float bd; int bi;
    if (d1 < d0 || (d1 == d0 && i1 < i0)) { bd = d1; bi = i1; } else { bd = d0; bi = i0; }
    float b2 = fminf(fminf(s0, s1), fmaxf(d0, d1));
    int rrow = n0 + tid;
    idx_out[rrow] = bi;
    loss_part[rrow] = bd;
    if (b2 - bd < THETA) {
      int p = atomicAdd(flag_cnt, 1);
      flag_list[p] = rrow;
    }
  }
#undef STAGE4
}

// ---------------------------------------------------------------------------
// coalesced exact-fp32 repair: one block per flagged row; thread owns 4
// consecutive e via float4 reads of embT (L2-resident); sequential-k fmaf
// chain + round-1-certified d formula + first-index tie-break.
__global__ __launch_bounds__(256) void repair_kernel(
    const float* __restrict__ z, const float* __restrict__ embT,
    const float* __restrict__ znorm, const float* __restrict__ enorm,
    const int* __restrict__ flag_cnt, const int* __restrict__ flag_list,
    int* __restrict__ idx_out) {
  __shared__ float zrow[256];
  __shared__ float rd[256];
  __shared__ int   ri[256];
  const int t = threadIdx.x;
  const int cnt = flag_cnt[0] < NROWS ? flag_cnt[0] : NROWS;
  const float4* embT4 = reinterpret_cast<const float4*>(embT);
  for (int j = blockIdx.x; j < cnt; j += gridDim.x) {
    const int n = flag_list[j];
    __syncthreads();
    zrow[t] = z[(size_t)(n >> 10) * ZB_STRIDE + (size_t)t * 1024 + (n & 1023)];
    __syncthreads();
    const float zn = znorm[n];
    float4 dot = {0.f, 0.f, 0.f, 0.f};
    for (int k = 0; k < 256; ++k) {
      float4 v = embT4[k * 256 + t];
      float s = zrow[k];
      dot.x = fmaf(s, v.x, dot.x);
      dot.y = fmaf(s, v.y, dot.y);
      dot.z = fmaf(s, v.z, dot.z);
      dot.w = fmaf(s, v.w, dot.w);
    }
    float bd = 3.4e38f; int bi = 0;
    const float dv[4] = {dot.x, dot.y, dot.z, dot.w};
#pragma unroll
    for (int q = 0; q < 4; ++q) {
      int e = t * 4 + q;
      float d = __fsub_rn(__fadd_rn(zn, enorm[e]), __fmul_rn(2.0f, dv[q]));
      if (d < bd) { bd = d; bi = e; }
    }
    rd[t] = bd; ri[t] = bi;
    __syncthreads();
    for (int s2 = 128; s2 > 0; s2 >>= 1) {
      if (t < s2) {
        float od = rd[t + s2]; int oi = ri[t + s2];
        if (od < rd[t] || (od == rd[t] && oi < ri[t])) { rd[t] = od; ri[t] = oi; }
      }
      __syncthreads();
    }
    if (t == 0) idx_out[n] = ri[0];
  }
}

// ---------------------------------------------------------------------------
__global__ __launch_bounds__(256) void onehot_kernel(const int* __restrict__ idx,
                                                     float* __restrict__ out_enc) {
  for (int i = blockIdx.x * 256 + threadIdx.x; i < NROWS * 256; i += 2048 * 256) {
    int n = i >> 8, j4 = i & 255;
    int e = idx[n];
    float4 v = {0.f, 0.f, 0.f, 0.f};
    if ((e >> 2) == j4) ((float*)&v)[e & 3] = 1.0f;
    reinterpret_cast<float4*>(out_enc)[i] = v;
  }
}

__global__ __launch_bounds__(256) void idxf_hist_kernel(const int* __restrict__ idx,
                                                        float* __restrict__ out_idxf,
                                                        int* __restrict__ hist) {
  int n = blockIdx.x * 256 + threadIdx.x;
  int e = idx[n];
  out_idxf[n] = (float)e;
  atomicAdd(&hist[e], 1);
}

__global__ __launch_bounds__(256) void gather_kernel(const float* __restrict__ emb,
                                                     const int* __restrict__ idx,
                                                     float* __restrict__ zq_out) {
  int bh = blockIdx.x;
  int b = bh >> 5, h = bh & 31;
  int t = threadIdx.x;
  int ww = t & 31;
  int gg = t >> 5;
  int n = b * 1024 + h * 32 + ww;
  int e = idx[n];
  const float* eb = emb + (size_t)e * CDIM;
  float* ob = zq_out + (size_t)b * ZB_STRIDE + h * 32 + ww;
#pragma unroll
  for (int u = 0; u < 32; ++u) {
    int c = gg * 32 + u;
    ob[(size_t)c * 1024] = eb[c];
  }
}

__global__ __launch_bounds__(256) void finalize_kernel(const float* __restrict__ loss_part,
                                                       const int* __restrict__ hist,
                                                       float* __restrict__ out_loss,
                                                       float* __restrict__ out_perp) {
  __shared__ float red[256];
  int t = threadIdx.x;
  float sum = 0.f;
  for (int i = t; i < NROWS; i += 256) sum += loss_part[i];
  red[t] = sum;
  __syncthreads();
  for (int s2 = 128; s2 > 0; s2 >>= 1) {
    if (t < s2) red[t] += red[t + s2];
    __syncthreads();
  }
  if (t == 0) out_loss[0] = 1.25f * (red[0] / 8388608.0f);
  __syncthreads();
  float hs = 0.f;
  for (int i = t; i < 1024; i += 256) {
    float em = (float)hist[i] / 32768.0f;
    hs += em * logf(em + 1e-10f);
  }
  red[t] = hs;
  __syncthreads();
  for (int s2 = 128; s2 > 0; s2 >>= 1) {
    if (t < s2) red[t] += red[t + s2];
    __syncthreads();
  }
  if (t == 0) out_perp[0] = expf(-red[0]);
}

// ---------------------------------------------------------------------------
extern "C" void kernel_launch(void* const* d_in, const int* in_sizes, int n_in,
                              void* d_out, int out_size, void* d_ws, size_t ws_size,
                              hipStream_t stream) {
  const float* z   = (const float*)d_in[0];
  const float* emb = (const float*)d_in[1];
  float* out = (float*)d_out;

  float* out_zq   = out + ZQ_OFF;
  float* out_loss = out + LOSS_OFF;
  float* out_perp = out + PERP_OFF;
  float* out_enc  = out + ENC_OFF;
  float* out_idxf = out + IDX_OFF;

  // workspace (small)
  int*   idx       = (int*)d_ws;                   // 32768
  int*   hist      = idx + NROWS;                  // 1024
  int*   flag_cnt  = hist + NE;                    // 4 (1 used)
  int*   flag_list = flag_cnt + 4;                 // 32768
  float* loss_part = (float*)(flag_list + NROWS);  // 32768
  float* znorm     = loss_part + NROWS;            // 32768
  float* enorm     = znorm + NROWS;                // 1024

  // staging buffers carved from the one-hot output region (overwritten later)
  unsigned short* zhi  = (unsigned short*)(out_enc + 2);   // 8388608 u16 (16B-aligned)
  unsigned short* ehi  = zhi + (size_t)NROWS * CDIM;       // 262144
  unsigned short* zlo  = ehi + (size_t)NE * CDIM;          // 8388608
  unsigned short* elo  = zlo + (size_t)NROWS * CDIM;       // 262144
  float*          embT = (float*)(elo + (size_t)NE * CDIM);// 262144 f32

  hipMemsetAsync(hist, 0, NE * sizeof(int), stream);
  hipMemsetAsync(flag_cnt, 0, sizeof(int), stream);

  convert_z_kernel<<<512, 256, 0, stream>>>(z, zhi, zlo, znorm);
  convert_e_kernel<<<128, 256, 0, stream>>>(emb, ehi, elo);
  enorm_kernel<<<NE / 256, 256, 0, stream>>>(emb, enorm);
  transpose_e_kernel<<<256, 256, 0, stream>>>(emb, embT);
  argmin_mfma3<<<NROWS / 128, 256, 0, stream>>>(zhi, zlo, ehi, elo, znorm, enorm,
                                                idx, loss_part, flag_cnt, flag_list);
  repair_kernel<<<1024, 256, 0, stream>>>(z, embT, znorm, enorm, flag_cnt, flag_list, idx);
  onehot_kernel<<<2048, 256, 0, stream>>>(idx, out_enc);
  idxf_hist_kernel<<<NROWS / 256, 256, 0, stream>>>(idx, out_idxf, hist);
  gather_kernel<<<1024, 256, 0, stream>>>(emb, idx, out_zq);
  finalize_kernel<<<1, 256, 0, stream>>>(loss_part, hist, out_loss, out_perp);
}

// Round 4
// 288.519 us; speedup vs baseline: 1.2560x; 1.0714x over previous
//
#include <hip/hip_runtime.h>
#include <math.h>

#define NROWS 32768
#define NE    1024
#define CDIM  256
#define ZB_STRIDE 262144

#define ZQ_OFF   0
#define LOSS_OFF 8388608
#define PERP_OFF 8388609
#define ENC_OFF  8388610
#define IDX_OFF  41943042

#define THETA 1.0e-4f

typedef __attribute__((ext_vector_type(8))) short bf16x8;
typedef __attribute__((ext_vector_type(4))) float f32x4;
typedef __attribute__((ext_vector_type(8))) unsigned short ushort8;

// RNE float -> bf16 bits
__device__ __forceinline__ unsigned short f2bf(float f) {
  union { float f; unsigned u; } v; v.f = f;
  unsigned r = v.u + 0x7FFFu + ((v.u >> 16) & 1u);
  return (unsigned short)(r >> 16);
}
__device__ __forceinline__ float bf2f(unsigned short b) {
  union { float f; unsigned u; } v; v.u = ((unsigned)b) << 16;
  return v.f;
}

// async global->LDS, 16B per lane
__device__ __forceinline__ void gl_lds16(const unsigned short* g, char* l) {
  __builtin_amdgcn_global_load_lds(
      (const __attribute__((address_space(1))) unsigned short*)g,
      (__attribute__((address_space(3))) char*)l, 16, 0, 0);
}

// ---------------------------------------------------------------------------
// numpy-pairwise-exact sum of squares (stride 1)
__device__ __forceinline__ float np_sumsq_256_s1(const float* __restrict__ base) {
  float tot[2];
#pragma unroll
  for (int hh = 0; hh < 2; ++hh) {
    float r[8];
#pragma unroll
    for (int j = 0; j < 8; ++j) {
      float x = base[hh * 128 + j];
      r[j] = __fmul_rn(x, x);
    }
    for (int i = 8; i < 128; i += 8) {
#pragma unroll
      for (int j = 0; j < 8; ++j) {
        float x = base[hh * 128 + i + j];
        r[j] = __fadd_rn(r[j], __fmul_rn(x, x));
      }
    }
    tot[hh] = __fadd_rn(__fadd_rn(__fadd_rn(r[0], r[1]), __fadd_rn(r[2], r[3])),
                        __fadd_rn(__fadd_rn(r[4], r[5]), __fadd_rn(r[6], r[7])));
  }
  return __fadd_rn(tot[0], tot[1]);
}

__global__ __launch_bounds__(256) void enorm_kernel(const float* __restrict__ emb,
                                                    float* __restrict__ enorm) {
  int n = blockIdx.x * 256 + threadIdx.x;
  enorm[n] = np_sumsq_256_s1(emb + (size_t)n * CDIM);
}

// emb fp32 -> bf16 hi + lo
__global__ __launch_bounds__(256) void convert_e_kernel(const float* __restrict__ emb,
                                                        unsigned short* __restrict__ ehi,
                                                        unsigned short* __restrict__ elo) {
  int i = (blockIdx.x * 256 + threadIdx.x) * 8;
  ushort8 oh, ol;
#pragma unroll
  for (int j = 0; j < 8; ++j) {
    float x = emb[i + j];
    unsigned short h = f2bf(x);
    oh[j] = h;
    ol[j] = f2bf(__fsub_rn(x, bf2f(h)));
  }
  *reinterpret_cast<ushort8*>(ehi + i) = oh;
  *reinterpret_cast<ushort8*>(elo + i) = ol;
}

// emb[e][c] -> embT[c][e] fp32 (for coalesced repair)
__global__ __launch_bounds__(256) void transpose_e_kernel(const float* __restrict__ emb,
                                                          float* __restrict__ embT) {
  __shared__ float tile[32][33];
  int be = blockIdx.x & 31, bc = blockIdx.x >> 5;
  int tx = threadIdx.x & 31, ty = threadIdx.x >> 5;
#pragma unroll
  for (int i = 0; i < 4; ++i)
    tile[ty + 8 * i][tx] = emb[(size_t)(be * 32 + ty + 8 * i) * 256 + bc * 32 + tx];
  __syncthreads();
#pragma unroll
  for (int i = 0; i < 4; ++i)
    embT[(size_t)(bc * 32 + ty + 8 * i) * 1024 + be * 32 + tx] = tile[tx][ty + 8 * i];
}

// ---------------------------------------------------------------------------
// z (b,c,h,w) fp32 -> zhi,zlo (n,c) bf16 transpose + numpy-exact znorm.
// Vectorized float4 loads (1KB per wave-instr). Thread (hh,jj,hw4) owns the
// np accumulator chain r_jj^hh for 4 hw's: c = hh*128 + jj + 8i, i ascending
// -- identical add tree to np_sumsq (certified round 1).
__global__ __launch_bounds__(256) void convert_z_kernel(const float* __restrict__ z,
                                                        unsigned short* __restrict__ zhi,
                                                        unsigned short* __restrict__ zlo,
                                                        float* __restrict__ znorm) {
  __shared__ unsigned short T16[64][266];
  __shared__ unsigned short Tlo[64][266];
  __shared__ float accsF[2][8][16][4];
  const int t = threadIdx.x;
  const int b = blockIdx.x >> 4, hwt = blockIdx.x & 15;
  const int hw0 = hwt * 64;
  const int hw4 = t & 15;          // float4 unit within 64 hw
  const int jj = (t >> 4) & 7;     // np accumulator index
  const int hh = t >> 7;           // half
  const float* zb = z + (size_t)b * ZB_STRIDE + hw0 + hw4 * 4;

  float rr[4];
#pragma unroll
  for (int i = 0; i < 16; ++i) {
    int c = hh * 128 + jj + 8 * i;
    float4 v = *reinterpret_cast<const float4*>(zb + (size_t)c * 1024);
    const float xv[4] = {v.x, v.y, v.z, v.w};
#pragma unroll
    for (int q = 0; q < 4; ++q) {
      float p = __fmul_rn(xv[q], xv[q]);
      rr[q] = (i == 0) ? p : __fadd_rn(rr[q], p);
      unsigned short hbits = f2bf(xv[q]);
      T16[hw4 * 4 + q][c] = hbits;
      Tlo[hw4 * 4 + q][c] = f2bf(__fsub_rn(xv[q], bf2f(hbits)));
    }
  }
#pragma unroll
  for (int q = 0; q < 4; ++q) accsF[hh][jj][hw4][q] = rr[q];
  __syncthreads();

  if (t < 64) {
    const int h4 = t >> 2, cq = t & 3;
    float tot[2];
#pragma unroll
    for (int half = 0; half < 2; ++half) {
      float r[8];
#pragma unroll
      for (int j = 0; j < 8; ++j) r[j] = accsF[half][j][h4][cq];
      tot[half] = __fadd_rn(__fadd_rn(__fadd_rn(r[0], r[1]), __fadd_rn(r[2], r[3])),
                            __fadd_rn(__fadd_rn(r[4], r[5]), __fadd_rn(r[6], r[7])));
    }
    znorm[b * 1024 + hw0 + t] = __fadd_rn(tot[0], tot[1]);
  }

  // write phase: thread -> row hww, 64 c's
  const int hww = t >> 2, cqq = (t & 3) * 64;
  size_t obase = ((size_t)(b * 1024 + hw0 + hww)) * 256 + cqq;
#pragma unroll
  for (int v = 0; v < 8; ++v) {
    ushort8 oh, ol;
#pragma unroll
    for (int j = 0; j < 8; ++j) {
      oh[j] = T16[hww][cqq + v * 8 + j];
      ol[j] = Tlo[hww][cqq + v * 8 + j];
    }
    *reinterpret_cast<ushort8*>(zhi + obase + v * 8) = oh;
    *reinterpret_cast<ushort8*>(zlo + obase + v * 8) = ol;
  }
}

// ---------------------------------------------------------------------------
// m97-style tiled 3-product split-bf16 MFMA argmin.
// Grid 2048: mb = bid>>3 (128-row panel), nb = bid&7 (128-e panel).
// Effective K = 768 over segments (zhi.ehi, zhi.elo, zlo.ehi), BK=64,
// single-buffered 32KB LDS, 2 barriers per K-step, 4 waves in 2x2.
// Emits per-(row, nb) top-2 (bd, bi, b2) for the merge kernel.
__global__ __launch_bounds__(256) void argmin_tile(
    const unsigned short* __restrict__ zhi, const unsigned short* __restrict__ zlo,
    const unsigned short* __restrict__ ehi, const unsigned short* __restrict__ elo,
    const float* __restrict__ znorm, const float* __restrict__ enorm,
    float* __restrict__ pbd, int* __restrict__ pbi, float* __restrict__ pb2) {
  __shared__ __align__(16) char As[16384];
  __shared__ __align__(16) char Bs[16384];

  const int tid = threadIdx.x;
  const int lane = tid & 63, w = tid >> 6;
  const int wr = w >> 1, wc = w & 1;
  const int l15 = lane & 15, g = lane >> 4;
  const int nb = blockIdx.x & 7;
  const int n0 = (blockIdx.x >> 3) * 128;
  const int e0 = nb * 128;

  float znr[4][4];
#pragma unroll
  for (int mi = 0; mi < 4; ++mi)
#pragma unroll
    for (int rg = 0; rg < 4; ++rg)
      znr[mi][rg] = znorm[n0 + wr * 64 + mi * 16 + g * 4 + rg];

  // stage one 128x64 bf16 tile (16KB), 128B rows, XOR swizzle ((row&7)<<4),
  // source pre-swizzled (rule 21)
#define STAGE(SRC, DST, ROWBASE, KELEM)                                        \
  {                                                                            \
    _Pragma("unroll")                                                          \
    for (int i = 0; i < 4; ++i) {                                              \
      int off = i * 4096 + tid * 16;                                           \
      int row = off >> 7, cb = off & 127;                                      \
      int csb = cb ^ ((row & 7) << 4);                                         \
      gl_lds16(SRC + (size_t)((ROWBASE) + row) * 256 + (KELEM) + (csb >> 1),   \
               DST + off);                                                     \
    }                                                                          \
  }

  f32x4 acc[4][4];
  const f32x4 z4 = {0.f, 0.f, 0.f, 0.f};
#pragma unroll
  for (int mi = 0; mi < 4; ++mi)
#pragma unroll
    for (int nj = 0; nj < 4; ++nj) acc[mi][nj] = z4;

  for (int s = 0; s < 12; ++s) {
    const unsigned short* Asrc = (s < 8) ? zhi : zlo;
    const unsigned short* Bsrc = (s >= 4 && s < 8) ? elo : ehi;
    const int kelem = (s & 3) * 64;
    __syncthreads();              // previous compute done before overwrite
    STAGE(Asrc, As, n0, kelem);
    STAGE(Bsrc, Bs, e0, kelem);
    __syncthreads();              // compiler drains vmcnt(0) before barrier
#pragma unroll
    for (int ks = 0; ks < 2; ++ks) {
      bf16x8 af[4], bv[4];
#pragma unroll
      for (int mi = 0; mi < 4; ++mi) {
        int rr = wr * 64 + mi * 16 + l15;
        int cc = (ks * 64 + g * 16) ^ ((rr & 7) << 4);
        af[mi] = *reinterpret_cast<const bf16x8*>(&As[rr * 128 + cc]);
      }
#pragma unroll
      for (int nj = 0; nj < 4; ++nj) {
        int er = wc * 64 + nj * 16 + l15;
        int cc = (ks * 64 + g * 16) ^ ((er & 7) << 4);
        bv[nj] = *reinterpret_cast<const bf16x8*>(&Bs[er * 128 + cc]);
      }
#pragma unroll
      for (int mi = 0; mi < 4; ++mi)
#pragma unroll
        for (int nj = 0; nj < 4; ++nj)
          acc[mi][nj] = __builtin_amdgcn_mfma_f32_16x16x32_bf16(af[mi], bv[nj], acc[mi][nj], 0, 0, 0);
    }
  }

  // epilogue: d = fmaf(-2, dot, zn+en), top-2 within this 128-e tile
  float bestd[4][4], b2d[4][4]; int besti[4][4];
#pragma unroll
  for (int mi = 0; mi < 4; ++mi)
#pragma unroll
    for (int rg = 0; rg < 4; ++rg) { bestd[mi][rg] = 3.4e38f; b2d[mi][rg] = 3.4e38f; besti[mi][rg] = 0; }

#pragma unroll
  for (int nj = 0; nj < 4; ++nj) {
    int e = e0 + wc * 64 + nj * 16 + l15;
    float en = enorm[e];
#pragma unroll
    for (int mi = 0; mi < 4; ++mi)
#pragma unroll
      for (int rg = 0; rg < 4; ++rg) {
        float d = fmaf(-2.0f, acc[mi][nj][rg], __fadd_rn(znr[mi][rg], en));
        if (d < bestd[mi][rg]) {
          b2d[mi][rg] = bestd[mi][rg]; bestd[mi][rg] = d; besti[mi][rg] = e;
        } else if (d < b2d[mi][rg]) {
          b2d[mi][rg] = d;
        }
      }
  }

  __syncthreads();  // all LDS reads done before reduction reuse
  float* redd = reinterpret_cast<float*>(&As[0]);
  int*   redi = reinterpret_cast<int*>(&As[0] + 1024);
  float* red2 = reinterpret_cast<float*>(&As[0] + 2048);

#pragma unroll
  for (int mi = 0; mi < 4; ++mi)
#pragma unroll
    for (int rg = 0; rg < 4; ++rg) {
      float bd = bestd[mi][rg]; int bi = besti[mi][rg]; float b2 = b2d[mi][rg];
#pragma unroll
      for (int m = 1; m < 16; m <<= 1) {
        float od = __shfl_xor(bd, m, 64);
        int   oi = __shfl_xor(bi, m, 64);
        float o2 = __shfl_xor(b2, m, 64);
        float hi = fmaxf(bd, od);
        b2 = fminf(fminf(b2, o2), hi);
        if (od < bd || (od == bd && oi < bi)) { bd = od; bi = oi; }
      }
      if (l15 == 0) {
        int lr = wr * 64 + mi * 16 + g * 4 + rg;
        redd[lr * 2 + wc] = bd; redi[lr * 2 + wc] = bi; red2[lr * 2 + wc] = b2;
      }
    }
  __syncthreads();

  if (tid < 128) {
    float d0 = redd[tid * 2], d1 = redd[tid * 2 + 1];
    int   i0 = redi[tid * 2], i1 = redi[tid * 2 + 1];
    float s0 = red2[tid * 2], s1 = red2[tid * 2 + 1];
    float bd; int bi;
    if (d1 < d0 || (d1 == d0 && i1 < i0)) { bd = d1; bi = i1; } else { bd = d0; bi = i0; }
    float b2 = fminf(fminf(s0, s1), fmaxf(d0, d1));
    size_t o = (size_t)(n0 + tid) * 8 + nb;
    pbd[o] = bd; pbi[o] = bi; pb2[o] = b2;
  }
#undef STAGE
}

// ---------------------------------------------------------------------------
// merge 8 per-block top-2 candidates per row; exact first-index tie-break
__global__ __launch_bounds__(256) void merge_kernel(
    const float* __restrict__ pbd, const int* __restrict__ pbi,
    const float* __restrict__ pb2,
    int* __restrict__ idx_out, float* __restrict__ loss_part,
    int* __restrict__ flag_cnt, int* __restrict__ flag_list) {
  int n = blockIdx.x * 256 + threadIdx.x;
  float bd = 3.4e38f; int bi = 0x7FFFFFFF; int bnb = -1;
#pragma unroll
  for (int nb = 0; nb < 8; ++nb) {
    float d = pbd[(size_t)n * 8 + nb];
    int   i = pbi[(size_t)n * 8 + nb];
    if (d < bd || (d == bd && i < bi)) { bd = d; bi = i; bnb = nb; }
  }
  float b2 = 3.4e38f;
#pragma unroll
  for (int nb = 0; nb < 8; ++nb) {
    float v = (nb == bnb) ? pb2[(size_t)n * 8 + nb] : pbd[(size_t)n * 8 + nb];
    b2 = fminf(b2, v);
  }
  idx_out[n] = bi;
  loss_part[n] = bd;
  if (b2 - bd < THETA) {
    int p = atomicAdd(flag_cnt, 1);
    flag_list[p] = n;
  }
}

// ---------------------------------------------------------------------------
// coalesced exact-fp32 repair (round-1-certified arithmetic)
__global__ __launch_bounds__(256) void repair_kernel(
    const float* __restrict__ z, const float* __restrict__ embT,
    const float* __restrict__ znorm, const float* __restrict__ enorm,
    const int* __restrict__ flag_cnt, const int* __restrict__ flag_list,
    int* __restrict__ idx_out) {
  __shared__ float zrow[256];
  __shared__ float rd[256];
  __shared__ int   ri[256];
  const int t = threadIdx.x;
  const int cnt = flag_cnt[0] < NROWS ? flag_cnt[0] : NROWS;
  const float4* embT4 = reinterpret_cast<const float4*>(embT);
  for (int j = blockIdx.x; j < cnt; j += gridDim.x) {
    const int n = flag_list[j];
    __syncthreads();
    zrow[t] = z[(size_t)(n >> 10) * ZB_STRIDE + (size_t)t * 1024 + (n & 1023)];
    __syncthreads();
    const float zn = znorm[n];
    float4 dot = {0.f, 0.f, 0.f, 0.f};
    for (int k = 0; k < 256; ++k) {
      float4 v = embT4[k * 256 + t];
      float s = zrow[k];
      dot.x = fmaf(s, v.x, dot.x);
      dot.y = fmaf(s, v.y, dot.y);
      dot.z = fmaf(s, v.z, dot.z);
      dot.w = fmaf(s, v.w, dot.w);
    }
    float bd = 3.4e38f; int bi = 0;
    const float dv[4] = {dot.x, dot.y, dot.z, dot.w};
#pragma unroll
    for (int q = 0; q < 4; ++q) {
      int e = t * 4 + q;
      float d = __fsub_rn(__fadd_rn(zn, enorm[e]), __fmul_rn(2.0f, dv[q]));
      if (d < bd) { bd = d; bi = e; }
    }
    rd[t] = bd; ri[t] = bi;
    __syncthreads();
    for (int s2 = 128; s2 > 0; s2 >>= 1) {
      if (t < s2) {
        float od = rd[t + s2]; int oi = ri[t + s2];
        if (od < rd[t] || (od == rd[t] && oi < ri[t])) { rd[t] = od; ri[t] = oi; }
      }
      __syncthreads();
    }
    if (t == 0) idx_out[n] = ri[0];
  }
}

// ---------------------------------------------------------------------------
__global__ __launch_bounds__(256) void onehot_kernel(const int* __restrict__ idx,
                                                     float* __restrict__ out_enc) {
  for (int i = blockIdx.x * 256 + threadIdx.x; i < NROWS * 256; i += 2048 * 256) {
    int n = i >> 8, j4 = i & 255;
    int e = idx[n];
    float4 v = {0.f, 0.f, 0.f, 0.f};
    if ((e >> 2) == j4) ((float*)&v)[e & 3] = 1.0f;
    reinterpret_cast<float4*>(out_enc)[i] = v;
  }
}

__global__ __launch_bounds__(256) void idxf_hist_kernel(const int* __restrict__ idx,
                                                        float* __restrict__ out_idxf,
                                                        int* __restrict__ hist) {
  int n = blockIdx.x * 256 + threadIdx.x;
  int e = idx[n];
  out_idxf[n] = (float)e;
  atomicAdd(&hist[e], 1);
}

__global__ __launch_bounds__(256) void gather_kernel(const float* __restrict__ emb,
                                                     const int* __restrict__ idx,
                                                     float* __restrict__ zq_out) {
  int bh = blockIdx.x;
  int b = bh >> 5, h = bh & 31;
  int t = threadIdx.x;
  int ww = t & 31;
  int gg = t >> 5;
  int n = b * 1024 + h * 32 + ww;
  int e = idx[n];
  const float* eb = emb + (size_t)e * CDIM;
  float* ob = zq_out + (size_t)b * ZB_STRIDE + h * 32 + ww;
#pragma unroll
  for (int u = 0; u < 32; ++u) {
    int c = gg * 32 + u;
    ob[(size_t)c * 1024] = eb[c];
  }
}

__global__ __launch_bounds__(256) void finalize_kernel(const float* __restrict__ loss_part,
                                                       const int* __restrict__ hist,
                                                       float* __restrict__ out_loss,
                                                       float* __restrict__ out_perp) {
  __shared__ float red[256];
  int t = threadIdx.x;
  float sum = 0.f;
  for (int i = t; i < NROWS; i += 256) sum += loss_part[i];
  red[t] = sum;
  __syncthreads();
  for (int s2 = 128; s2 > 0; s2 >>= 1) {
    if (t < s2) red[t] += red[t + s2];
    __syncthreads();
  }
  if (t == 0) out_loss[0] = 1.25f * (red[0] / 8388608.0f);
  __syncthreads();
  float hs = 0.f;
  for (int i = t; i < 1024; i += 256) {
    float em = (float)hist[i] / 32768.0f;
    hs += em * logf(em + 1e-10f);
  }
  red[t] = hs;
  __syncthreads();
  for (int s2 = 128; s2 > 0; s2 >>= 1) {
    if (t < s2) red[t] += red[t + s2];
    __syncthreads();
  }
  if (t == 0) out_perp[0] = expf(-red[0]);
}

// ---------------------------------------------------------------------------
extern "C" void kernel_launch(void* const* d_in, const int* in_sizes, int n_in,
                              void* d_out, int out_size, void* d_ws, size_t ws_size,
                              hipStream_t stream) {
  const float* z   = (const float*)d_in[0];
  const float* emb = (const float*)d_in[1];
  float* out = (float*)d_out;

  float* out_zq   = out + ZQ_OFF;
  float* out_loss = out + LOSS_OFF;
  float* out_perp = out + PERP_OFF;
  float* out_enc  = out + ENC_OFF;
  float* out_idxf = out + IDX_OFF;

  // workspace (small)
  int*   idx       = (int*)d_ws;                   // 32768
  int*   hist      = idx + NROWS;                  // 1024
  int*   flag_cnt  = hist + NE;                    // 4 (1 used)
  int*   flag_list = flag_cnt + 4;                 // 32768
  float* loss_part = (float*)(flag_list + NROWS);  // 32768
  float* znorm     = loss_part + NROWS;            // 32768
  float* enorm     = znorm + NROWS;                // 1024

  // staging buffers carved from the one-hot output region (overwritten later)
  unsigned short* zhi  = (unsigned short*)(out_enc + 2);   // 8388608 u16 (16B-aligned)
  unsigned short* ehi  = zhi + (size_t)NROWS * CDIM;       // 262144
  unsigned short* zlo  = ehi + (size_t)NE * CDIM;          // 8388608
  unsigned short* elo  = zlo + (size_t)NROWS * CDIM;       // 262144
  float*          embT = (float*)(elo + (size_t)NE * CDIM);// 262144 f32
  float*          pbd  = embT + 262144;                    // 262144 f32
  int*            pbi  = (int*)(pbd + 262144);             // 262144 i32
  float*          pb2  = (float*)(pbi + 262144);           // 262144 f32

  hipMemsetAsync(hist, 0, NE * sizeof(int), stream);
  hipMemsetAsync(flag_cnt, 0, sizeof(int), stream);

  convert_z_kernel<<<512, 256, 0, stream>>>(z, zhi, zlo, znorm);
  convert_e_kernel<<<128, 256, 0, stream>>>(emb, ehi, elo);
  enorm_kernel<<<NE / 256, 256, 0, stream>>>(emb, enorm);
  transpose_e_kernel<<<256, 256, 0, stream>>>(emb, embT);
  argmin_tile<<<2048, 256, 0, stream>>>(zhi, zlo, ehi, elo, znorm, enorm, pbd, pbi, pb2);
  merge_kernel<<<NROWS / 256, 256, 0, stream>>>(pbd, pbi, pb2, idx, loss_part, flag_cnt, flag_list);
  repair_kernel<<<1024, 256, 0, stream>>>(z, embT, znorm, enorm, flag_cnt, flag_list, idx);
  onehot_kernel<<<2048, 256, 0, stream>>>(idx, out_enc);
  idxf_hist_kernel<<<NROWS / 256, 256, 0, stream>>>(idx, out_idxf, hist);
  gather_kernel<<<1024, 256, 0, stream>>>(emb, idx, out_zq);
  finalize_kernel<<<1, 256, 0, stream>>>(loss_part, hist, out_loss, out_perp);
}

// Round 5
// 275.650 us; speedup vs baseline: 1.3146x; 1.0467x over previous
//
#include <hip/hip_runtime.h>
#include <math.h>

#define NROWS 32768
#define NE    1024
#define CDIM  256
#define ZB_STRIDE 262144

#define ZQ_OFF   0
#define LOSS_OFF 8388608
#define PERP_OFF 8388609
#define ENC_OFF  8388610
#define IDX_OFF  41943042

#define THETA 1.0e-4f

typedef __attribute__((ext_vector_type(8))) short bf16x8;
typedef __attribute__((ext_vector_type(4))) float f32x4;
typedef __attribute__((ext_vector_type(8))) unsigned short ushort8;

// RNE float -> bf16 bits
__device__ __forceinline__ unsigned short f2bf(float f) {
  union { float f; unsigned u; } v; v.f = f;
  unsigned r = v.u + 0x7FFFu + ((v.u >> 16) & 1u);
  return (unsigned short)(r >> 16);
}
__device__ __forceinline__ float bf2f(unsigned short b) {
  union { float f; unsigned u; } v; v.u = ((unsigned)b) << 16;
  return v.f;
}

// async global->LDS, 16B per lane
__device__ __forceinline__ void gl_lds16(const unsigned short* g, char* l) {
  __builtin_amdgcn_global_load_lds(
      (const __attribute__((address_space(1))) unsigned short*)g,
      (__attribute__((address_space(3))) char*)l, 16, 0, 0);
}

// ---------------------------------------------------------------------------
// numpy-pairwise-exact sum of squares (stride 1)
__device__ __forceinline__ float np_sumsq_256_s1(const float* __restrict__ base) {
  float tot[2];
#pragma unroll
  for (int hh = 0; hh < 2; ++hh) {
    float r[8];
#pragma unroll
    for (int j = 0; j < 8; ++j) {
      float x = base[hh * 128 + j];
      r[j] = __fmul_rn(x, x);
    }
    for (int i = 8; i < 128; i += 8) {
#pragma unroll
      for (int j = 0; j < 8; ++j) {
        float x = base[hh * 128 + i + j];
        r[j] = __fadd_rn(r[j], __fmul_rn(x, x));
      }
    }
    tot[hh] = __fadd_rn(__fadd_rn(__fadd_rn(r[0], r[1]), __fadd_rn(r[2], r[3])),
                        __fadd_rn(__fadd_rn(r[4], r[5]), __fadd_rn(r[6], r[7])));
  }
  return __fadd_rn(tot[0], tot[1]);
}

__global__ __launch_bounds__(256) void enorm_kernel(const float* __restrict__ emb,
                                                    float* __restrict__ enorm) {
  int n = blockIdx.x * 256 + threadIdx.x;
  enorm[n] = np_sumsq_256_s1(emb + (size_t)n * CDIM);
}

// emb fp32 -> bf16 hi + lo
__global__ __launch_bounds__(256) void convert_e_kernel(const float* __restrict__ emb,
                                                        unsigned short* __restrict__ ehi,
                                                        unsigned short* __restrict__ elo) {
  int i = (blockIdx.x * 256 + threadIdx.x) * 8;
  ushort8 oh, ol;
#pragma unroll
  for (int j = 0; j < 8; ++j) {
    float x = emb[i + j];
    unsigned short h = f2bf(x);
    oh[j] = h;
    ol[j] = f2bf(__fsub_rn(x, bf2f(h)));
  }
  *reinterpret_cast<ushort8*>(ehi + i) = oh;
  *reinterpret_cast<ushort8*>(elo + i) = ol;
}

// emb[e][c] -> embT[c][e] fp32 (for coalesced repair)
__global__ __launch_bounds__(256) void transpose_e_kernel(const float* __restrict__ emb,
                                                          float* __restrict__ embT) {
  __shared__ float tile[32][33];
  int be = blockIdx.x & 31, bc = blockIdx.x >> 5;
  int tx = threadIdx.x & 31, ty = threadIdx.x >> 5;
#pragma unroll
  for (int i = 0; i < 4; ++i)
    tile[ty + 8 * i][tx] = emb[(size_t)(be * 32 + ty + 8 * i) * 256 + bc * 32 + tx];
  __syncthreads();
#pragma unroll
  for (int i = 0; i < 4; ++i)
    embT[(size_t)(bc * 32 + ty + 8 * i) * 1024 + be * 32 + tx] = tile[tx][ty + 8 * i];
}

// ---------------------------------------------------------------------------
// z (b,c,h,w) fp32 -> zhi,zlo (n,c) bf16 transpose + numpy-exact znorm.
__global__ __launch_bounds__(256) void convert_z_kernel(const float* __restrict__ z,
                                                        unsigned short* __restrict__ zhi,
                                                        unsigned short* __restrict__ zlo,
                                                        float* __restrict__ znorm) {
  __shared__ unsigned short T16[64][266];
  __shared__ unsigned short Tlo[64][266];
  __shared__ float accsF[2][8][16][4];
  const int t = threadIdx.x;
  const int b = blockIdx.x >> 4, hwt = blockIdx.x & 15;
  const int hw0 = hwt * 64;
  const int hw4 = t & 15;          // float4 unit within 64 hw
  const int jj = (t >> 4) & 7;     // np accumulator index
  const int hh = t >> 7;           // half
  const float* zb = z + (size_t)b * ZB_STRIDE + hw0 + hw4 * 4;

  float rr[4];
#pragma unroll
  for (int i = 0; i < 16; ++i) {
    int c = hh * 128 + jj + 8 * i;
    float4 v = *reinterpret_cast<const float4*>(zb + (size_t)c * 1024);
    const float xv[4] = {v.x, v.y, v.z, v.w};
#pragma unroll
    for (int q = 0; q < 4; ++q) {
      float p = __fmul_rn(xv[q], xv[q]);
      rr[q] = (i == 0) ? p : __fadd_rn(rr[q], p);
      unsigned short hbits = f2bf(xv[q]);
      T16[hw4 * 4 + q][c] = hbits;
      Tlo[hw4 * 4 + q][c] = f2bf(__fsub_rn(xv[q], bf2f(hbits)));
    }
  }
#pragma unroll
  for (int q = 0; q < 4; ++q) accsF[hh][jj][hw4][q] = rr[q];
  __syncthreads();

  if (t < 64) {
    const int h4 = t >> 2, cq = t & 3;
    float tot[2];
#pragma unroll
    for (int half = 0; half < 2; ++half) {
      float r[8];
#pragma unroll
      for (int j = 0; j < 8; ++j) r[j] = accsF[half][j][h4][cq];
      tot[half] = __fadd_rn(__fadd_rn(__fadd_rn(r[0], r[1]), __fadd_rn(r[2], r[3])),
                            __fadd_rn(__fadd_rn(r[4], r[5]), __fadd_rn(r[6], r[7])));
    }
    znorm[b * 1024 + hw0 + t] = __fadd_rn(tot[0], tot[1]);
  }

  // write phase: thread -> row hww, 64 c's
  const int hww = t >> 2, cqq = (t & 3) * 64;
  size_t obase = ((size_t)(b * 1024 + hw0 + hww)) * 256 + cqq;
#pragma unroll
  for (int v = 0; v < 8; ++v) {
    ushort8 oh, ol;
#pragma unroll
    for (int j = 0; j < 8; ++j) {
      oh[j] = T16[hww][cqq + v * 8 + j];
      ol[j] = Tlo[hww][cqq + v * 8 + j];
    }
    *reinterpret_cast<ushort8*>(zhi + obase + v * 8) = oh;
    *reinterpret_cast<ushort8*>(zlo + obase + v * 8) = ol;
  }
}

// ---------------------------------------------------------------------------
// m97-style tiled 3-product split-bf16 MFMA argmin, v2:
//  * XCD-bijective swizzle: all 8 e-tiles of a row panel land on ONE XCD
//    (A panel fetched from HBM once, then L2-hits) [T1 / rule from m192]
//  * T3 2-phase prefetch: double-buffered LDS, STAGE(s+1) issued before
//    compute(s), one vmcnt-drain barrier per K-step [T3 minimal recipe]
// LDS layout / swizzle / arithmetic identical to round 4 (0 conflicts).
__global__ __launch_bounds__(256) void argmin_tile(
    const unsigned short* __restrict__ zhi, const unsigned short* __restrict__ zlo,
    const unsigned short* __restrict__ ehi, const unsigned short* __restrict__ elo,
    const float* __restrict__ znorm, const float* __restrict__ enorm,
    float* __restrict__ pbd, int* __restrict__ pbi, float* __restrict__ pb2) {
  __shared__ __align__(16) char As[2][16384];
  __shared__ __align__(16) char Bs[2][16384];

  const int tid = threadIdx.x;
  const int lane = tid & 63, w = tid >> 6;
  const int wr = w >> 1, wc = w & 1;
  const int l15 = lane & 15, g = lane >> 4;

  // XCD swizzle: xcd = bid&7 (HW round-robin), 32 row-panels x 8 e-tiles per XCD
  const int bid = blockIdx.x;
  const int nb = (bid >> 3) & 7;
  const int mb = (bid & 7) * 32 + (bid >> 6);
  const int n0 = mb * 128;
  const int e0 = nb * 128;

  float znr[4][4];
#pragma unroll
  for (int mi = 0; mi < 4; ++mi)
#pragma unroll
    for (int rg = 0; rg < 4; ++rg)
      znr[mi][rg] = znorm[n0 + wr * 64 + mi * 16 + g * 4 + rg];

  // precomputed staging offsets: 128x64 bf16 tile (16KB), 128B rows,
  // XOR swizzle ((row&7)<<4), source pre-swizzled (rule 21)
  int ldsoff[4], grow[4], gcol[4];
#pragma unroll
  for (int i = 0; i < 4; ++i) {
    int off = i * 4096 + tid * 16;
    int row = off >> 7, cb = off & 127;
    int csb = cb ^ ((row & 7) << 4);
    ldsoff[i] = off; grow[i] = row; gcol[i] = csb >> 1;
  }

#define STAGE(SRC, DST, ROWBASE, KELEM)                                        \
  {                                                                            \
    _Pragma("unroll")                                                          \
    for (int i = 0; i < 4; ++i)                                                \
      gl_lds16(SRC + (size_t)((ROWBASE) + grow[i]) * 256 + (KELEM) + gcol[i],  \
               DST + ldsoff[i]);                                               \
  }

  f32x4 acc[4][4];
  const f32x4 z4 = {0.f, 0.f, 0.f, 0.f};
#pragma unroll
  for (int mi = 0; mi < 4; ++mi)
#pragma unroll
    for (int nj = 0; nj < 4; ++nj) acc[mi][nj] = z4;

  // segment s: A = zhi (s<8) | zlo (s>=8); B = ehi (s<4, s>=8) | elo (4..7)
  STAGE(zhi, As[0], n0, 0);
  STAGE(ehi, Bs[0], e0, 0);
  __syncthreads();

  int buf = 0;
  for (int s = 0; s < 12; ++s) {
    if (s + 1 < 12) {
      const unsigned short* An = (s + 1 < 8) ? zhi : zlo;
      const unsigned short* Bn = (s + 1 >= 4 && s + 1 < 8) ? elo : ehi;
      const int kn = ((s + 1) & 3) * 64;
      STAGE(An, As[buf ^ 1], n0, kn);
      STAGE(Bn, Bs[buf ^ 1], e0, kn);
    }
#pragma unroll
    for (int ks = 0; ks < 2; ++ks) {
      bf16x8 af[4], bv[4];
#pragma unroll
      for (int mi = 0; mi < 4; ++mi) {
        int rr = wr * 64 + mi * 16 + l15;
        int cc = (ks * 64 + g * 16) ^ ((rr & 7) << 4);
        af[mi] = *reinterpret_cast<const bf16x8*>(&As[buf][rr * 128 + cc]);
      }
#pragma unroll
      for (int nj = 0; nj < 4; ++nj) {
        int er = wc * 64 + nj * 16 + l15;
        int cc = (ks * 64 + g * 16) ^ ((er & 7) << 4);
        bv[nj] = *reinterpret_cast<const bf16x8*>(&Bs[buf][er * 128 + cc]);
      }
#pragma unroll
      for (int mi = 0; mi < 4; ++mi)
#pragma unroll
        for (int nj = 0; nj < 4; ++nj)
          acc[mi][nj] = __builtin_amdgcn_mfma_f32_16x16x32_bf16(af[mi], bv[nj], acc[mi][nj], 0, 0, 0);
    }
    __syncthreads();   // drains prefetch vmcnt + guards buffer reuse
    buf ^= 1;
  }

  // epilogue: d = fmaf(-2, dot, zn+en), top-2 within this 128-e tile
  float bestd[4][4], b2d[4][4]; int besti[4][4];
#pragma unroll
  for (int mi = 0; mi < 4; ++mi)
#pragma unroll
    for (int rg = 0; rg < 4; ++rg) { bestd[mi][rg] = 3.4e38f; b2d[mi][rg] = 3.4e38f; besti[mi][rg] = 0; }

#pragma unroll
  for (int nj = 0; nj < 4; ++nj) {
    int e = e0 + wc * 64 + nj * 16 + l15;
    float en = enorm[e];
#pragma unroll
    for (int mi = 0; mi < 4; ++mi)
#pragma unroll
      for (int rg = 0; rg < 4; ++rg) {
        float d = fmaf(-2.0f, acc[mi][nj][rg], __fadd_rn(znr[mi][rg], en));
        if (d < bestd[mi][rg]) {
          b2d[mi][rg] = bestd[mi][rg]; bestd[mi][rg] = d; besti[mi][rg] = e;
        } else if (d < b2d[mi][rg]) {
          b2d[mi][rg] = d;
        }
      }
  }

  float* redd = reinterpret_cast<float*>(&As[0][0]);
  int*   redi = reinterpret_cast<int*>(&As[0][0] + 1024);
  float* red2 = reinterpret_cast<float*>(&As[0][0] + 2048);

#pragma unroll
  for (int mi = 0; mi < 4; ++mi)
#pragma unroll
    for (int rg = 0; rg < 4; ++rg) {
      float bd = bestd[mi][rg]; int bi = besti[mi][rg]; float b2 = b2d[mi][rg];
#pragma unroll
      for (int m = 1; m < 16; m <<= 1) {
        float od = __shfl_xor(bd, m, 64);
        int   oi = __shfl_xor(bi, m, 64);
        float o2 = __shfl_xor(b2, m, 64);
        float hi = fmaxf(bd, od);
        b2 = fminf(fminf(b2, o2), hi);
        if (od < bd || (od == bd && oi < bi)) { bd = od; bi = oi; }
      }
      if (l15 == 0) {
        int lr = wr * 64 + mi * 16 + g * 4 + rg;
        redd[lr * 2 + wc] = bd; redi[lr * 2 + wc] = bi; red2[lr * 2 + wc] = b2;
      }
    }
  __syncthreads();

  if (tid < 128) {
    float d0 = redd[tid * 2], d1 = redd[tid * 2 + 1];
    int   i0 = redi[tid * 2], i1 = redi[tid * 2 + 1];
    float s0 = red2[tid * 2], s1 = red2[tid * 2 + 1];
    float bd; int bi;
    if (d1 < d0 || (d1 == d0 && i1 < i0)) { bd = d1; bi = i1; } else { bd = d0; bi = i0; }
    float b2 = fminf(fminf(s0, s1), fmaxf(d0, d1));
    size_t o = (size_t)(n0 + tid) * 8 + nb;
    pbd[o] = bd; pbi[o] = bi; pb2[o] = b2;
  }
#undef STAGE
}

// ---------------------------------------------------------------------------
// merge 8 per-block top-2 candidates per row; exact first-index tie-break
__global__ __launch_bounds__(256) void merge_kernel(
    const float* __restrict__ pbd, const int* __restrict__ pbi,
    const float* __restrict__ pb2,
    int* __restrict__ idx_out, float* __restrict__ loss_part,
    int* __restrict__ flag_cnt, int* __restrict__ flag_list) {
  int n = blockIdx.x * 256 + threadIdx.x;
  float bd = 3.4e38f; int bi = 0x7FFFFFFF; int bnb = -1;
#pragma unroll
  for (int nb = 0; nb < 8; ++nb) {
    float d = pbd[(size_t)n * 8 + nb];
    int   i = pbi[(size_t)n * 8 + nb];
    if (d < bd || (d == bd && i < bi)) { bd = d; bi = i; bnb = nb; }
  }
  float b2 = 3.4e38f;
#pragma unroll
  for (int nb = 0; nb < 8; ++nb) {
    float v = (nb == bnb) ? pb2[(size_t)n * 8 + nb] : pbd[(size_t)n * 8 + nb];
    b2 = fminf(b2, v);
  }
  idx_out[n] = bi;
  loss_part[n] = bd;
  if (b2 - bd < THETA) {
    int p = atomicAdd(flag_cnt, 1);
    flag_list[p] = n;
  }
}

// ---------------------------------------------------------------------------
// coalesced exact-fp32 repair (round-1-certified arithmetic)
__global__ __launch_bounds__(256) void repair_kernel(
    const float* __restrict__ z, const float* __restrict__ embT,
    const float* __restrict__ znorm, const float* __restrict__ enorm,
    const int* __restrict__ flag_cnt, const int* __restrict__ flag_list,
    int* __restrict__ idx_out) {
  __shared__ float zrow[256];
  __shared__ float rd[256];
  __shared__ int   ri[256];
  const int t = threadIdx.x;
  const int cnt = flag_cnt[0] < NROWS ? flag_cnt[0] : NROWS;
  const float4* embT4 = reinterpret_cast<const float4*>(embT);
  for (int j = blockIdx.x; j < cnt; j += gridDim.x) {
    const int n = flag_list[j];
    __syncthreads();
    zrow[t] = z[(size_t)(n >> 10) * ZB_STRIDE + (size_t)t * 1024 + (n & 1023)];
    __syncthreads();
    const float zn = znorm[n];
    float4 dot = {0.f, 0.f, 0.f, 0.f};
    for (int k = 0; k < 256; ++k) {
      float4 v = embT4[k * 256 + t];
      float s = zrow[k];
      dot.x = fmaf(s, v.x, dot.x);
      dot.y = fmaf(s, v.y, dot.y);
      dot.z = fmaf(s, v.z, dot.z);
      dot.w = fmaf(s, v.w, dot.w);
    }
    float bd = 3.4e38f; int bi = 0;
    const float dv[4] = {dot.x, dot.y, dot.z, dot.w};
#pragma unroll
    for (int q = 0; q < 4; ++q) {
      int e = t * 4 + q;
      float d = __fsub_rn(__fadd_rn(zn, enorm[e]), __fmul_rn(2.0f, dv[q]));
      if (d < bd) { bd = d; bi = e; }
    }
    rd[t] = bd; ri[t] = bi;
    __syncthreads();
    for (int s2 = 128; s2 > 0; s2 >>= 1) {
      if (t < s2) {
        float od = rd[t + s2]; int oi = ri[t + s2];
        if (od < rd[t] || (od == rd[t] && oi < ri[t])) { rd[t] = od; ri[t] = oi; }
      }
      __syncthreads();
    }
    if (t == 0) idx_out[n] = ri[0];
  }
}

// ---------------------------------------------------------------------------
__global__ __launch_bounds__(256) void onehot_kernel(const int* __restrict__ idx,
                                                     float* __restrict__ out_enc) {
  for (int i = blockIdx.x * 256 + threadIdx.x; i < NROWS * 256; i += 2048 * 256) {
    int n = i >> 8, j4 = i & 255;
    int e = idx[n];
    float4 v = {0.f, 0.f, 0.f, 0.f};
    if ((e >> 2) == j4) ((float*)&v)[e & 3] = 1.0f;
    reinterpret_cast<float4*>(out_enc)[i] = v;
  }
}

__global__ __launch_bounds__(256) void idxf_hist_kernel(const int* __restrict__ idx,
                                                        float* __restrict__ out_idxf,
                                                        int* __restrict__ hist) {
  int n = blockIdx.x * 256 + threadIdx.x;
  int e = idx[n];
  out_idxf[n] = (float)e;
  atomicAdd(&hist[e], 1);
}

__global__ __launch_bounds__(256) void gather_kernel(const float* __restrict__ emb,
                                                     const int* __restrict__ idx,
                                                     float* __restrict__ zq_out) {
  int bh = blockIdx.x;
  int b = bh >> 5, h = bh & 31;
  int t = threadIdx.x;
  int ww = t & 31;
  int gg = t >> 5;
  int n = b * 1024 + h * 32 + ww;
  int e = idx[n];
  const float* eb = emb + (size_t)e * CDIM;
  float* ob = zq_out + (size_t)b * ZB_STRIDE + h * 32 + ww;
#pragma unroll
  for (int u = 0; u < 32; ++u) {
    int c = gg * 32 + u;
    ob[(size_t)c * 1024] = eb[c];
  }
}

__global__ __launch_bounds__(256) void finalize_kernel(const float* __restrict__ loss_part,
                                                       const int* __restrict__ hist,
                                                       float* __restrict__ out_loss,
                                                       float* __restrict__ out_perp) {
  __shared__ float red[256];
  int t = threadIdx.x;
  float sum = 0.f;
  for (int i = t; i < NROWS; i += 256) sum += loss_part[i];
  red[t] = sum;
  __syncthreads();
  for (int s2 = 128; s2 > 0; s2 >>= 1) {
    if (t < s2) red[t] += red[t + s2];
    __syncthreads();
  }
  if (t == 0) out_loss[0] = 1.25f * (red[0] / 8388608.0f);
  __syncthreads();
  float hs = 0.f;
  for (int i = t; i < 1024; i += 256) {
    float em = (float)hist[i] / 32768.0f;
    hs += em * logf(em + 1e-10f);
  }
  red[t] = hs;
  __syncthreads();
  for (int s2 = 128; s2 > 0; s2 >>= 1) {
    if (t < s2) red[t] += red[t + s2];
    __syncthreads();
  }
  if (t == 0) out_perp[0] = expf(-red[0]);
}

// ---------------------------------------------------------------------------
extern "C" void kernel_launch(void* const* d_in, const int* in_sizes, int n_in,
                              void* d_out, int out_size, void* d_ws, size_t ws_size,
                              hipStream_t stream) {
  const float* z   = (const float*)d_in[0];
  const float* emb = (const float*)d_in[1];
  float* out = (float*)d_out;

  float* out_zq   = out + ZQ_OFF;
  float* out_loss = out + LOSS_OFF;
  float* out_perp = out + PERP_OFF;
  float* out_enc  = out + ENC_OFF;
  float* out_idxf = out + IDX_OFF;

  // workspace (small)
  int*   idx       = (int*)d_ws;                   // 32768
  int*   hist      = idx + NROWS;                  // 1024
  int*   flag_cnt  = hist + NE;                    // 4 (1 used)
  int*   flag_list = flag_cnt + 4;                 // 32768
  float* loss_part = (float*)(flag_list + NROWS);  // 32768
  float* znorm     = loss_part + NROWS;            // 32768
  float* enorm     = znorm + NROWS;                // 1024

  // staging buffers carved from the one-hot output region (overwritten later)
  unsigned short* zhi  = (unsigned short*)(out_enc + 2);   // 8388608 u16 (16B-aligned)
  unsigned short* ehi  = zhi + (size_t)NROWS * CDIM;       // 262144
  unsigned short* zlo  = ehi + (size_t)NE * CDIM;          // 8388608
  unsigned short* elo  = zlo + (size_t)NROWS * CDIM;       // 262144
  float*          embT = (float*)(elo + (size_t)NE * CDIM);// 262144 f32
  float*          pbd  = embT + 262144;                    // 262144 f32
  int*            pbi  = (int*)(pbd + 262144);             // 262144 i32
  float*          pb2  = (float*)(pbi + 262144);           // 262144 f32

  hipMemsetAsync(hist, 0, NE * sizeof(int), stream);
  hipMemsetAsync(flag_cnt, 0, sizeof(int), stream);

  convert_z_kernel<<<512, 256, 0, stream>>>(z, zhi, zlo, znorm);
  convert_e_kernel<<<128, 256, 0, stream>>>(emb, ehi, elo);
  enorm_kernel<<<NE / 256, 256, 0, stream>>>(emb, enorm);
  transpose_e_kernel<<<256, 256, 0, stream>>>(emb, embT);
  argmin_tile<<<2048, 256, 0, stream>>>(zhi, zlo, ehi, elo, znorm, enorm, pbd, pbi, pb2);
  merge_kernel<<<NROWS / 256, 256, 0, stream>>>(pbd, pbi, pb2, idx, loss_part, flag_cnt, flag_list);
  repair_kernel<<<1024, 256, 0, stream>>>(z, embT, znorm, enorm, flag_cnt, flag_list, idx);
  onehot_kernel<<<2048, 256, 0, stream>>>(idx, out_enc);
  idxf_hist_kernel<<<NROWS / 256, 256, 0, stream>>>(idx, out_idxf, hist);
  gather_kernel<<<1024, 256, 0, stream>>>(emb, idx, out_zq);
  finalize_kernel<<<1, 256, 0, stream>>>(loss_part, hist, out_loss, out_perp);
}